// Round 8
// baseline (172.338 us; speedup 1.0000x reference)
//
#include <hip/hip_runtime.h>
#include <math.h>

#define NELEC 10
#define NSPIN 2
#define NPER 5
#define DIM 3
#define NION 2
#define DP 32
#define NDENSE 64
#define NPERM 120
#define RS 324   // G row stride (words): the 5 selectable rows land on disjoint bank quads.

// R23: stage-3 GEMM moved to the (idle) MFMA pipe with exact fp16 two-split.
// V = H@W1 computed as (Ha+Hb)@(Wa+Wb) in 4 mfma_f32_16x16x32_f16 products:
// fp16 products are exact in the fp32 accumulator, so the only error is the split
// residual ~2^-22 rel (fp32-class; far below the accepted fast_tanh deviation).
// A/B k-layout safety: both operands are stored with the SAME (group,elem)->k
// formula, so any internal HW k-permutation cancels (k-sum is permutation
// invariant); C/D layout is the m89-verified col=lane&15,row=(lane>>4)*4+reg.
//
// Per-spin pool (words): b1L[64]@0, w2L[64]@64, overlay@128:
//   stage A: s1e[160]@128, G[5][324]@288..1908
//   stage B: park[2 splits][128 rows][20 words]@128..5248  (rows 16B-aligned,
//            20-word stride -> 2-way bank aliasing = free)
// POOL = 5248 words -> block LDS ~42.6 KB.
#define B1OFF 0
#define W2OFF 64
#define OVL 128
#define GOFF (OVL + 160)
#define PSTR 2560      // park: words per split region
#define PROW 20        // park: words per row (32 fp16 payload + pad)
#define POOL_WORDS (OVL + 2 * PSTR)   // 5248

typedef _Float16 f16x8 __attribute__((ext_vector_type(8)));
typedef float f32x4 __attribute__((ext_vector_type(4)));

// tanh(x) = 1 - 2*rcp(exp(2x)+1): ~1-2 ulp, exact at saturation. Validated R5-R22.
__device__ __forceinline__ float fast_tanh(float x) {
    float e = __expf(2.0f * x);
    return 1.0f - 2.0f * __builtin_amdgcn_rcpf(e + 1.0f);
}

__device__ __forceinline__ unsigned pick_remove(unsigned& el, int d) {
    unsigned v = (el >> (4 * d)) & 0xFu;
    unsigned low = el & ((1u << (4 * d)) - 1u);
    el = low | ((el >> (4 * (d + 1))) << (4 * d));
    return v;
}

__device__ __forceinline__ float perm_sign(int p) {
    int d0 = p / 24; int r0 = p - 24 * d0;
    int d1 = r0 / 6; int r1 = r0 - 6 * d1;
    int d2 = r1 >> 1; int d3 = r1 & 1;
    return ((d0 + d1 + d2 + d3) & 1) ? -1.f : 1.f;
}

// ---------------- prep: split W1 into fp16 hi/lo, transposed [split][s][j][k] ----------------
__global__ __launch_bounds__(256) void prep_w1(const float* __restrict__ w1,
                                               _Float16* __restrict__ wsp)
{
    int idx = blockIdx.x * 256 + threadIdx.x;        // 0..8191
    if (idx < NSPIN * NDENSE * NDENSE) {
        int s = idx >> 12; int r = idx & 4095; int k = r >> 6; int j = r & 63;
        float x = w1[s * 4096 + k * 64 + j];
        _Float16 hi = (_Float16)x;
        float rem = x - (float)hi;                   // exact
        _Float16 lo = (_Float16)rem;
        wsp[((0 * NSPIN + s) * 64 + j) * 64 + k] = hi;
        wsp[((1 * NSPIN + s) * 64 + j) * 64 + k] = lo;
    }
}

// ---------------- fused: one block per batch element, 4 waves = 2 spin-pairs ----------------
__global__ __launch_bounds__(256, 1) void antisym_fused(
    const float* __restrict__ elec_pos, const float* __restrict__ ion_pos,
    const float* __restrict__ bf_w, const float* __restrict__ bf_b,
    const float* __restrict__ w0, const float* __restrict__ b0,
    const float* __restrict__ b1, const float* __restrict__ w2,
    const float* __restrict__ jk, const _Float16* __restrict__ wsp,
    float* __restrict__ out, int B)
{
    const int b = blockIdx.x;
    const int t = threadIdx.x;
    const int s = t >> 7;                   // spin: waves 0-1 -> 0, waves 2-3 -> 1
    const int ts = t & 127;                 // thread within the spin-pair
    const int wave = (t >> 6) & 1;          // wave within the spin-pair
    const int lane = t & 63;

    __shared__ __align__(16) float pool[NSPIN][POOL_WORDS];   // 2 x 20992 B
    __shared__ float signT[128];
    __shared__ double red_h[NSPIN][2];
    __shared__ double red_j[NSPIN][2];
    __shared__ float jterm[2 * NELEC];

    float* b1L = pool[s] + B1OFF;                             // [64]
    float* w2L = pool[s] + W2OFF;                             // [64]
    float* s1e = pool[s] + OVL;                               // [160]  (stage A)
    #define GROW(j) (pool[s] + GOFF + (j) * RS)               // G[j][.] (stage A)
    // park: PARKP(split) + row*PROW + c*4 words              (stage B overlay)
    #define PARKP(sp) (pool[s] + OVL + (sp) * PSTR)

    // ---- stage 1: stream_1e = tanh(feats @ bf_w + bf_b), this spin's 5 electrons ----
    const float* ep = elec_pos + (b * NELEC + s * NPER) * DIM;
    const float i0x = ion_pos[0], i0y = ion_pos[1], i0z = ion_pos[2];
    const float i1x = ion_pos[3], i1y = ion_pos[4], i1z = ion_pos[5];
    for (int idx = ts; idx < NPER * DP; idx += 128) {
        int j = idx >> 5, c = idx & 31;
        float ex = ep[j * 3 + 0], ey = ep[j * 3 + 1], ez = ep[j * 3 + 2];
        float dx0 = ex - i0x, dy0 = ey - i0y, dz0 = ez - i0z;
        float dx1 = ex - i1x, dy1 = ey - i1y, dz1 = ez - i1z;
        float n0 = sqrtf(dx0 * dx0 + dy0 * dy0 + dz0 * dz0);
        float n1 = sqrtf(dx1 * dx1 + dy1 * dy1 + dz1 * dz1);
        float acc = bf_b[c];
        acc += dx0 * bf_w[0 * DP + c];
        acc += dy0 * bf_w[1 * DP + c];
        acc += dz0 * bf_w[2 * DP + c];
        acc += dx1 * bf_w[3 * DP + c];
        acc += dy1 * bf_w[4 * DP + c];
        acc += dz1 * bf_w[5 * DP + c];
        acc += n0 * bf_w[6 * DP + c];
        acc += n1 * bf_w[7 * DP + c];
        s1e[idx] = fast_tanh(acc);
    }
    // b1/w2 -> LDS (epilogue reads them after the overlay clobbers nothing here)
    if (ts < NDENSE) {
        b1L[ts] = b1[s * NDENSE + ts];
        w2L[ts] = w2[s * NDENSE + ts];
    }
    // permutation sign LUT (shared across spins; rows 120-127 = padding -> 0)
    if (t < 128) signT[t] = (t < NPERM) ? perm_sign(t) : 0.f;
    // jastrow terms (combine's exact per-term math; summed e-major by t0 later)
    if (t < 2 * NELEC) {
        int e = t >> 1, ion = t & 1;
        const float* epb = elec_pos + b * NELEC * DIM;
        float ex = epb[e * 3 + 0], ey = epb[e * 3 + 1], ez = epb[e * 3 + 2];
        float ix = ion_pos[ion * 3 + 0], iy = ion_pos[ion * 3 + 1], iz = ion_pos[ion * 3 + 2];
        float dx = ex - ix, dy = ey - iy, dz = ez - iz;
        jterm[t] = jk[ion] * sqrtf(dx * dx + dy * dy + dz * dz);
    }
    __syncthreads();

    // ---- stage 2: G[j][i*64+c] = s1e[j][:] @ w0[s][32i:32i+32, c] ----
    // Slice-outer with wcol[32] in registers (R14-validated): 96 global loads/wave.
    const float* w0s = w0 + s * (NPER * DP) * NDENSE;   // [160][64]
    #pragma unroll
    for (int m = 0; m < 3; m++) {
        const int i = wave + 2 * m;         // wave0: i=0,2,4  wave1: i=1,3 (m=2 skipped)
        if (i < NPER) {                     // wave-uniform branch
            float wcol[DP];
            #pragma unroll
            for (int k = 0; k < DP; k++) wcol[k] = w0s[(i * DP + k) * NDENSE + lane];
            #pragma unroll
            for (int j = 0; j < NPER; j++) {
                float acc = 0.f;
                #pragma unroll
                for (int q = 0; q < 8; q++) {
                    float4 sv = *(const float4*)(s1e + j * DP + q * 4);   // LDS broadcast
                    acc += sv.x * wcol[q * 4 + 0];
                    acc += sv.y * wcol[q * 4 + 1];
                    acc += sv.z * wcol[q * 4 + 2];
                    acc += sv.w * wcol[q * 4 + 3];
                }
                GROW(j)[i * NDENSE + lane] = acc;
            }
        }
    }
    __syncthreads();

    const float* b0s = b0 + s * NDENSE;
    const float* w2s = w2 + s * NDENSE;     // w2 is [s][64][1]

    // ---- stage 3 phase 1: lane = perm. h built, split to fp16 hi/lo in registers ----
    const int pid = wave * 60 + lane;
    float sign = 0.f;
    int p0 = 0, p1 = 0, p2 = 0, p3 = 0, p4 = 0;
    if (lane < 60) {
        int p = pid;
        unsigned el = 0x43210u;
        int d0 = p / 24; p -= d0 * 24;
        int d1 = p / 6;  p -= d1 * 6;
        int d2 = p / 2;  p -= d2 * 2;
        int d3 = p;
        p0 = pick_remove(el, d0);
        p1 = pick_remove(el, d1);
        p2 = pick_remove(el, d2);
        p3 = pick_remove(el, d3);
        p4 = el & 0xF;
        sign = ((d0 + d1 + d2 + d3) & 1) ? -1.f : 1.f;
    }
    const float* g0 = GROW(p0) + 0 * NDENSE;
    const float* g1 = GROW(p1) + 1 * NDENSE;
    const float* g2 = GROW(p2) + 2 * NDENSE;
    const float* g3 = GROW(p3) + 3 * NDENSE;
    const float* g4 = GROW(p4) + 4 * NDENSE;

    f16x8 pkA[8], pkB[8];                   // h hi/lo splits: [chunk*4 + c], k = 8c'+e
    float hdot = 0.f;
    #pragma unroll
    for (int cc = 0; cc < NDENSE / 4; cc++) {
        float4 a = *(const float4*)(b0s + cc * 4);                    // uniform
        float4 q;
        q = *(const float4*)(g0 + cc * 4); a.x += q.x; a.y += q.y; a.z += q.z; a.w += q.w;
        q = *(const float4*)(g1 + cc * 4); a.x += q.x; a.y += q.y; a.z += q.z; a.w += q.w;
        q = *(const float4*)(g2 + cc * 4); a.x += q.x; a.y += q.y; a.z += q.z; a.w += q.w;
        q = *(const float4*)(g3 + cc * 4); a.x += q.x; a.y += q.y; a.z += q.z; a.w += q.w;
        q = *(const float4*)(g4 + cc * 4); a.x += q.x; a.y += q.y; a.z += q.z; a.w += q.w;
        float t0 = fast_tanh(a.x), t1 = fast_tanh(a.y), t2 = fast_tanh(a.z), t3 = fast_tanh(a.w);
        hdot += t0 * w2s[cc * 4 + 0] + t1 * w2s[cc * 4 + 1]
              + t2 * w2s[cc * 4 + 2] + t3 * w2s[cc * 4 + 3];
        // split & pack: k = cc*4+e -> vec idx (cc>>1 within chunk), elem 4*(cc&1)+e
        const int vi = (cc >> 3) * 4 + ((cc & 7) >> 1);
        const int po = 4 * (cc & 1);
        _Float16 h_; float r_;
        h_ = (_Float16)t0; r_ = t0 - (float)h_; pkA[vi][po + 0] = h_; pkB[vi][po + 0] = (_Float16)r_;
        h_ = (_Float16)t1; r_ = t1 - (float)h_; pkA[vi][po + 1] = h_; pkB[vi][po + 1] = (_Float16)r_;
        h_ = (_Float16)t2; r_ = t2 - (float)h_; pkA[vi][po + 2] = h_; pkB[vi][po + 2] = (_Float16)r_;
        h_ = (_Float16)t3; r_ = t3 - (float)h_; pkA[vi][po + 3] = h_; pkB[vi][po + 3] = (_Float16)r_;
    }

    double dvh = (double)(sign * hdot);     // sign=0 for lanes 60-63
    #pragma unroll
    for (int off = 32; off > 0; off >>= 1) dvh += __shfl_down(dvh, off, 64);
    if (lane == 0) red_h[s][wave] = dvh;

    // ---- stage 3 phase 2: V[128x64] = H @ W1 on the MFMA pipe, 2 k-chunks ----
    const int lg = lane >> 4, lr = lane & 15;
    const int prow = (lane < 60) ? pid : (120 + wave * 4 + (lane - 60));  // pad rows -> 0

    f16x8 zf;
    #pragma unroll
    for (int e = 0; e < 8; e++) zf[e] = (_Float16)0.f;

    f32x4 acc[4][4];                        // [mt][nt], this wave's 4 M-tiles
    #pragma unroll
    for (int mt = 0; mt < 4; mt++)
        #pragma unroll
        for (int nt = 0; nt < 4; nt++)
            #pragma unroll
            for (int e = 0; e < 4; e++) acc[mt][nt][e] = 0.f;

    #pragma unroll
    for (int ch = 0; ch < 2; ch++) {
        __syncthreads();                    // ch0: G reads done (park overlays G)
                                            // ch1: chunk-0 park reads done
        // park this k-chunk (both splits), rows 0..127, zeros for pad rows
        #pragma unroll
        for (int c = 0; c < 4; c++) {
            *(f16x8*)(PARKP(0) + prow * PROW + c * 4) = (lane < 60) ? pkA[ch * 4 + c] : zf;
            *(f16x8*)(PARKP(1) + prow * PROW + c * 4) = (lane < 60) ? pkB[ch * 4 + c] : zf;
        }
        __syncthreads();                    // park visible

        // B fragments: [split][s][j][k] fp16 from ws (L2-hot, 16B-aligned)
        f16x8 Ba[4], Bb[4];
        #pragma unroll
        for (int nt = 0; nt < 4; nt++) {
            Ba[nt] = *(const f16x8*)(wsp + ((0 * NSPIN + s) * 64 + nt * 16 + lr) * 64 + ch * 32 + lg * 8);
            Bb[nt] = *(const f16x8*)(wsp + ((1 * NSPIN + s) * 64 + nt * 16 + lr) * 64 + ch * 32 + lg * 8);
        }
        #pragma unroll
        for (int mt = 0; mt < 4; mt++) {
            const float* ar = PARKP(0) + (wave * 64 + mt * 16 + lr) * PROW + lg * 4;
            f16x8 Aa = *(const f16x8*)ar;
            f16x8 Ab = *(const f16x8*)(ar + PSTR);
            #pragma unroll
            for (int nt = 0; nt < 4; nt++) {
                acc[mt][nt] = __builtin_amdgcn_mfma_f32_16x16x32_f16(Ab, Bb[nt], acc[mt][nt], 0, 0, 0);
                acc[mt][nt] = __builtin_amdgcn_mfma_f32_16x16x32_f16(Ab, Ba[nt], acc[mt][nt], 0, 0, 0);
                acc[mt][nt] = __builtin_amdgcn_mfma_f32_16x16x32_f16(Aa, Bb[nt], acc[mt][nt], 0, 0, 0);
                acc[mt][nt] = __builtin_amdgcn_mfma_f32_16x16x32_f16(Aa, Ba[nt], acc[mt][nt], 0, 0, 0);
            }
        }
    }

    // ---- epilogue: lanesum = sum sgn[p] * tanh(V[p][j]+b1[j]) * w2[j] over owned (p,j)
    // C layout (m89-verified, dtype-independent): col j = nt*16 + (lane&15),
    // row p = wave*64 + mt*16 + (lane>>4)*4 + reg.
    float bv[4], wv[4];
    #pragma unroll
    for (int nt = 0; nt < 4; nt++) {
        bv[nt] = b1L[nt * 16 + lr];
        wv[nt] = w2L[nt * 16 + lr];
    }
    float lanesum = 0.f;
    #pragma unroll
    for (int mt = 0; mt < 4; mt++) {
        #pragma unroll
        for (int qr = 0; qr < 4; qr++) {
            const int p = wave * 64 + mt * 16 + lg * 4 + qr;
            float sgn = signT[p];           // 0 for pad rows 120..127
            float si = 0.f;
            #pragma unroll
            for (int nt = 0; nt < 4; nt++)
                si = fmaf(fast_tanh(acc[mt][nt][qr] + bv[nt]), wv[nt], si);
            lanesum = fmaf(sgn, si, lanesum);
        }
    }

    double dvj = (double)lanesum;
    #pragma unroll
    for (int off = 32; off > 0; off >>= 1) dvj += __shfl_down(dvj, off, 64);
    if (lane == 0) red_j[s][wave] = dvj;
    __syncthreads();

    // ---- inline combine (R13-validated) ----
    if (t == 0) {
        float ps0 = (float)((red_h[0][0] + red_h[0][1]) + (red_j[0][0] + red_j[0][1]));
        float ps1 = (float)((red_h[1][0] + red_h[1][1]) + (red_j[1][0] + red_j[1][1]));
        float jas = 0.f;
        #pragma unroll
        for (int i = 0; i < 2 * NELEC; i++) jas += jterm[i];
        out[b] = logf(fabsf(ps0 * ps1)) - jas;
    }
    // b2 omitted: sum_p sign_p = 0 kills it exactly.
}

extern "C" void kernel_launch(void* const* d_in, const int* in_sizes, int n_in,
                              void* d_out, int out_size, void* d_ws, size_t ws_size,
                              hipStream_t stream) {
    const float* elec_pos = (const float*)d_in[0];
    const float* ion_pos  = (const float*)d_in[1];
    const float* bf_w     = (const float*)d_in[2];
    const float* bf_b     = (const float*)d_in[3];
    const float* w0       = (const float*)d_in[4];
    const float* b0       = (const float*)d_in[5];
    const float* w1       = (const float*)d_in[6];
    const float* b1       = (const float*)d_in[7];
    const float* w2       = (const float*)d_in[8];
    const float* jk       = (const float*)d_in[10];
    float* out = (float*)d_out;
    _Float16* wsp = (_Float16*)d_ws;        // 2 splits x 2 spins x 64 x 64 fp16 = 32768 B

    const int B = in_sizes[0] / (NELEC * DIM);   // 2048

    hipLaunchKernelGGL(prep_w1, dim3(32), dim3(256), 0, stream, w1, wsp);
    hipLaunchKernelGGL(antisym_fused,
                       dim3(B), dim3(256), 0, stream,
                       elec_pos, ion_pos, bf_w, bf_b, w0, b0, b1, w2, jk, wsp, out, B);
}

// Round 9
// 153.789 us; speedup vs baseline: 1.1206x; 1.1206x over previous
//
#include <hip/hip_runtime.h>
#include <math.h>

#define NELEC 10
#define NSPIN 2
#define NPER 5
#define DIM 3
#define NION 2
#define DP 32
#define NDENSE 64
#define NPERM 120
#define RS 324   // G row stride (words): the 5 selectable rows land on disjoint bank quads.
#define HTS 124  // HT row stride (words): reads 2 addrs/bank-quad (free, m136); writes 2/bank free.

// FINAL (R24 = R21, session-best: bench 154.95us, rocprof 99.5us).
// Session conclusion: ~100us is a structural latency floor for this algorithm shape.
// Falsified levers: occupancy (R17/R20), barrier count/width (R18/R20), data-reuse
// shape (R19), prefetch depth (R21-null: compiler re-sinks source pipelines), vmem
// traffic (R22), and VALU issue count (R23: MFMA port cut VALU 45%, duration
// unchanged). Remaining idle (~37% at VALUBusy 63%) is per-block phase-transition
// latency across ~8 sequential block-rounds/CU, uncoverable at 2-3 convoy streams.
//
// Per-spin LDS pool with live-range overlay (R10/R12/R13-validated):
//   stage A: s1e[160] @ 0, G[5][324] @ 160..1780
//   stage B: HT[64][124] @ 0..7936
#define POOL_WORDS (NDENSE * HTS)

typedef float v2f __attribute__((ext_vector_type(2)));
typedef float v4f __attribute__((ext_vector_type(4)));

// Packed fp32 FMA (VOP3P), bit-identical to scalar v_fma pairs (R12-validated).
#define PK_FMA_LO(acc, hp, wp) \
    asm("v_pk_fma_f32 %0, %1, %2, %0 op_sel_hi:[1,0,1]" : "+v"(acc) : "v"(hp), "v"(wp))
#define PK_FMA_HI(acc, hp, wp) \
    asm("v_pk_fma_f32 %0, %1, %2, %0 op_sel:[0,1,0] op_sel_hi:[1,1,1]" : "+v"(acc) : "v"(hp), "v"(wp))

// tanh(x) = 1 - 2*rcp(exp(2x)+1): ~1-2 ulp, exact at saturation. Validated R5-R23.
__device__ __forceinline__ float fast_tanh(float x) {
    float e = __expf(2.0f * x);
    return 1.0f - 2.0f * __builtin_amdgcn_rcpf(e + 1.0f);
}

__device__ __forceinline__ unsigned pick_remove(unsigned& el, int d) {
    unsigned v = (el >> (4 * d)) & 0xFu;
    unsigned low = el & ((1u << (4 * d)) - 1u);
    el = low | ((el >> (4 * (d + 1))) << (4 * d));
    return v;
}

// ---------------- fused: one block per batch element, 4 waves = 2 spin-pairs ----------------
__global__ __launch_bounds__(256, 1) void antisym_fused(
    const float* __restrict__ elec_pos, const float* __restrict__ ion_pos,
    const float* __restrict__ bf_w, const float* __restrict__ bf_b,
    const float* __restrict__ w0, const float* __restrict__ b0,
    const float* __restrict__ w1, const float* __restrict__ b1,
    const float* __restrict__ w2, const float* __restrict__ jk,
    float* __restrict__ out, int B)
{
    const int b = blockIdx.x;
    const int t = threadIdx.x;
    const int s = t >> 7;                   // spin: waves 0-1 -> 0, waves 2-3 -> 1
    const int ts = t & 127;                 // thread within the spin-pair
    const int wave = (t >> 6) & 1;          // wave within the spin-pair
    const int lane = t & 63;

    __shared__ __align__(16) float pool[NSPIN][POOL_WORDS];   // 2 x 31744 B
    __shared__ double red_h[NSPIN][2];
    __shared__ double red_j[NSPIN][2];
    __shared__ float jterm[2 * NELEC];

    float* s1e = pool[s];                                     // [160]    (stage A)
    #define GROW(j) (pool[s] + 160 + (j) * RS)                // G[j][.]  (stage A)
    #define HTROW(k) (pool[s] + (k) * HTS)                    // HT[k][.] (stage B)

    // ---- stage 1: stream_1e = tanh(feats @ bf_w + bf_b), this spin's 5 electrons ----
    const float* ep = elec_pos + (b * NELEC + s * NPER) * DIM;
    const float i0x = ion_pos[0], i0y = ion_pos[1], i0z = ion_pos[2];
    const float i1x = ion_pos[3], i1y = ion_pos[4], i1z = ion_pos[5];
    for (int idx = ts; idx < NPER * DP; idx += 128) {
        int j = idx >> 5, c = idx & 31;
        float ex = ep[j * 3 + 0], ey = ep[j * 3 + 1], ez = ep[j * 3 + 2];
        float dx0 = ex - i0x, dy0 = ey - i0y, dz0 = ez - i0z;
        float dx1 = ex - i1x, dy1 = ey - i1y, dz1 = ez - i1z;
        float n0 = sqrtf(dx0 * dx0 + dy0 * dy0 + dz0 * dz0);
        float n1 = sqrtf(dx1 * dx1 + dy1 * dy1 + dz1 * dz1);
        float acc = bf_b[c];
        acc += dx0 * bf_w[0 * DP + c];
        acc += dy0 * bf_w[1 * DP + c];
        acc += dz0 * bf_w[2 * DP + c];
        acc += dx1 * bf_w[3 * DP + c];
        acc += dy1 * bf_w[4 * DP + c];
        acc += dz1 * bf_w[5 * DP + c];
        acc += n0 * bf_w[6 * DP + c];
        acc += n1 * bf_w[7 * DP + c];
        s1e[idx] = fast_tanh(acc);
    }
    // jastrow terms (combine's exact per-term math; summed e-major by t0 later)
    if (t < 2 * NELEC) {
        int e = t >> 1, ion = t & 1;
        const float* epb = elec_pos + b * NELEC * DIM;
        float ex = epb[e * 3 + 0], ey = epb[e * 3 + 1], ez = epb[e * 3 + 2];
        float ix = ion_pos[ion * 3 + 0], iy = ion_pos[ion * 3 + 1], iz = ion_pos[ion * 3 + 2];
        float dx = ex - ix, dy = ey - iy, dz = ez - iz;
        jterm[t] = jk[ion] * sqrtf(dx * dx + dy * dy + dz * dz);
    }
    __syncthreads();

    // ---- stage 2: G[j][i*64+c] = s1e[j][:] @ w0[s][32i:32i+32, c] ----
    // Slice-outer with wcol[32] in registers (R14-validated): 96 global loads/wave.
    const float* w0s = w0 + s * (NPER * DP) * NDENSE;   // [160][64]
    #pragma unroll
    for (int m = 0; m < 3; m++) {
        const int i = wave + 2 * m;         // wave0: i=0,2,4  wave1: i=1,3 (m=2 skipped)
        if (i < NPER) {                     // wave-uniform branch
            float wcol[DP];
            #pragma unroll
            for (int k = 0; k < DP; k++) wcol[k] = w0s[(i * DP + k) * NDENSE + lane];
            #pragma unroll
            for (int j = 0; j < NPER; j++) {
                float acc = 0.f;
                #pragma unroll
                for (int q = 0; q < 8; q++) {
                    float4 sv = *(const float4*)(s1e + j * DP + q * 4);   // LDS broadcast
                    acc += sv.x * wcol[q * 4 + 0];
                    acc += sv.y * wcol[q * 4 + 1];
                    acc += sv.z * wcol[q * 4 + 2];
                    acc += sv.w * wcol[q * 4 + 3];
                }
                GROW(j)[i * NDENSE + lane] = acc;
            }
        }
    }
    __syncthreads();

    const float* b0s = b0 + s * NDENSE;
    const float* w2s = w2 + s * NDENSE;     // w2 is [s][64][1]

    // ---- stage 3 phase 1: lane = perm. h_p built in registers (G still live) ----
    const int pid = wave * 60 + lane;
    float sign = 0.f;
    int p0 = 0, p1 = 0, p2 = 0, p3 = 0, p4 = 0;
    if (lane < 60) {
        int p = pid;
        unsigned el = 0x43210u;
        int d0 = p / 24; p -= d0 * 24;
        int d1 = p / 6;  p -= d1 * 6;
        int d2 = p / 2;  p -= d2 * 2;
        int d3 = p;
        p0 = pick_remove(el, d0);
        p1 = pick_remove(el, d1);
        p2 = pick_remove(el, d2);
        p3 = pick_remove(el, d3);
        p4 = el & 0xF;
        sign = ((d0 + d1 + d2 + d3) & 1) ? -1.f : 1.f;
    }
    const float* g0 = GROW(p0) + 0 * NDENSE;
    const float* g1 = GROW(p1) + 1 * NDENSE;
    const float* g2 = GROW(p2) + 2 * NDENSE;
    const float* g3 = GROW(p3) + 3 * NDENSE;
    const float* g4 = GROW(p4) + 4 * NDENSE;

    float h[NDENSE];                        // constant-indexed -> VGPR-resident
    float hdot = 0.f;
    #pragma unroll
    for (int cc = 0; cc < NDENSE / 4; cc++) {
        float4 a = *(const float4*)(b0s + cc * 4);                    // uniform -> s_load
        float4 q;
        q = *(const float4*)(g0 + cc * 4); a.x += q.x; a.y += q.y; a.z += q.z; a.w += q.w;
        q = *(const float4*)(g1 + cc * 4); a.x += q.x; a.y += q.y; a.z += q.z; a.w += q.w;
        q = *(const float4*)(g2 + cc * 4); a.x += q.x; a.y += q.y; a.z += q.z; a.w += q.w;
        q = *(const float4*)(g3 + cc * 4); a.x += q.x; a.y += q.y; a.z += q.z; a.w += q.w;
        q = *(const float4*)(g4 + cc * 4); a.x += q.x; a.y += q.y; a.z += q.z; a.w += q.w;
        float t0 = fast_tanh(a.x), t1 = fast_tanh(a.y), t2 = fast_tanh(a.z), t3 = fast_tanh(a.w);
        h[cc * 4 + 0] = t0; h[cc * 4 + 1] = t1; h[cc * 4 + 2] = t2; h[cc * 4 + 3] = t3;
        hdot += t0 * w2s[cc * 4 + 0] + t1 * w2s[cc * 4 + 1]
              + t2 * w2s[cc * 4 + 2] + t3 * w2s[cc * 4 + 3];
    }

    double dvh = (double)(sign * hdot);     // sign=0 for lanes 60-63
    #pragma unroll
    for (int off = 32; off > 0; off >>= 1) dvh += __shfl_down(dvh, off, 64);
    if (lane == 0) red_h[s][wave] = dvh;

    __syncthreads();                        // all G reads complete -> pool reusable

    // park h transposed: HT[k][pid] (b32 writes, consecutive pids -> 2 lanes/bank = free)
    if (lane < 60) {
        #pragma unroll
        for (int k = 0; k < NDENSE; k++) HTROW(k)[pid] = h[k];
    }
    __syncthreads();                        // HT visible

    // ---- stage 3 phase 2: 8x8 tile GEMM V[120x64] = H @ W1 (chunk-of-4 dbuf form) ----
    const int pg = lane >> 3, jg = lane & 7;
    const int pb = wave ? (56 + 8 * pg) : (8 * pg);
    const float* w1s = w1 + s * NDENSE * NDENSE;
    const float* b1s = b1 + s * NDENSE;
    const float* wgp = w1s + 8 * jg;        // this lane's j-octet in w1 row k

    v2f vp[4][8];
    #pragma unroll
    for (int ip = 0; ip < 4; ip++)
        #pragma unroll
        for (int r = 0; r < 8; r++) vp[ip][r] = (v2f)(0.f);

#define LDHT(DA, DB, kk) { DA = *(const v4f*)(&HTROW(kk)[pb]); DB = *(const v4f*)(&HTROW(kk)[pb + 4]); }
#define LDW1(DA, DB, kk) { DA = *(const v4f*)(wgp + (kk) * NDENSE); DB = *(const v4f*)(wgp + (kk) * NDENSE + 4); }
// One k-step: same FMA sequence as R13 (k order across steps ascending -> bit-identical).
#define STEP(HA, HB, WA, WB) do { \
    v2f hp0 = (HA).xy, hp1 = (HA).zw, hp2 = (HB).xy, hp3 = (HB).zw; \
    v2f wp0 = (WA).xy, wp1 = (WA).zw, wp2 = (WB).xy, wp3 = (WB).zw; \
    PK_FMA_LO(vp[0][0], hp0, wp0); PK_FMA_HI(vp[0][1], hp0, wp0); \
    PK_FMA_LO(vp[0][2], hp0, wp1); PK_FMA_HI(vp[0][3], hp0, wp1); \
    PK_FMA_LO(vp[0][4], hp0, wp2); PK_FMA_HI(vp[0][5], hp0, wp2); \
    PK_FMA_LO(vp[0][6], hp0, wp3); PK_FMA_HI(vp[0][7], hp0, wp3); \
    PK_FMA_LO(vp[1][0], hp1, wp0); PK_FMA_HI(vp[1][1], hp1, wp0); \
    PK_FMA_LO(vp[1][2], hp1, wp1); PK_FMA_HI(vp[1][3], hp1, wp1); \
    PK_FMA_LO(vp[1][4], hp1, wp2); PK_FMA_HI(vp[1][5], hp1, wp2); \
    PK_FMA_LO(vp[1][6], hp1, wp3); PK_FMA_HI(vp[1][7], hp1, wp3); \
    PK_FMA_LO(vp[2][0], hp2, wp0); PK_FMA_HI(vp[2][1], hp2, wp0); \
    PK_FMA_LO(vp[2][2], hp2, wp1); PK_FMA_HI(vp[2][3], hp2, wp1); \
    PK_FMA_LO(vp[2][4], hp2, wp2); PK_FMA_HI(vp[2][5], hp2, wp2); \
    PK_FMA_LO(vp[2][6], hp2, wp3); PK_FMA_HI(vp[2][7], hp2, wp3); \
    PK_FMA_LO(vp[3][0], hp3, wp0); PK_FMA_HI(vp[3][1], hp3, wp0); \
    PK_FMA_LO(vp[3][2], hp3, wp1); PK_FMA_HI(vp[3][3], hp3, wp1); \
    PK_FMA_LO(vp[3][4], hp3, wp2); PK_FMA_HI(vp[3][5], hp3, wp2); \
    PK_FMA_LO(vp[3][6], hp3, wp3); PK_FMA_HI(vp[3][7], hp3, wp3); \
} while (0)

    v4f ea0, eb0, ea1, eb1, ea2, eb2, ea3, eb3;
    v4f fa0, fb0, fa1, fb1, fa2, fb2, fa3, fb3;
    v4f xa0, xb0, xa1, xb1, xa2, xb2, xa3, xb3;
    v4f ya0, yb0, ya1, yb1, ya2, yb2, ya3, yb3;

    LDHT(ea0, eb0, 0); LDHT(ea1, eb1, 1); LDHT(ea2, eb2, 2); LDHT(ea3, eb3, 3);
    LDW1(xa0, xb0, 0); LDW1(xa1, xb1, 1); LDW1(xa2, xb2, 2); LDW1(xa3, xb3, 3);

    #pragma unroll 1
    for (int c2 = 0; c2 < 8; c2++) {
        const int k0 = c2 * 8;
        LDW1(ya0, yb0, k0 + 4); LDW1(ya1, yb1, k0 + 5);
        LDW1(ya2, yb2, k0 + 6); LDW1(ya3, yb3, k0 + 7);
        LDHT(fa0, fb0, k0 + 4); LDHT(fa1, fb1, k0 + 5);
        LDHT(fa2, fb2, k0 + 6); LDHT(fa3, fb3, k0 + 7);
        STEP(ea0, eb0, xa0, xb0); STEP(ea1, eb1, xa1, xb1);
        STEP(ea2, eb2, xa2, xb2); STEP(ea3, eb3, xa3, xb3);
        if (c2 < 7) {                       // wave-uniform guard (no OOB w1 reads)
            LDW1(xa0, xb0, k0 + 8);  LDW1(xa1, xb1, k0 + 9);
            LDW1(xa2, xb2, k0 + 10); LDW1(xa3, xb3, k0 + 11);
            LDHT(ea0, eb0, k0 + 8);  LDHT(ea1, eb1, k0 + 9);
            LDHT(ea2, eb2, k0 + 10); LDHT(ea3, eb3, k0 + 11);
        }
        STEP(fa0, fb0, ya0, yb0); STEP(fa1, fb1, ya1, yb1);
        STEP(fa2, fb2, ya2, yb2); STEP(fa3, fb3, ya3, yb3);
    }

    // epilogue: lanesum = sum_i sgn_i * sum_r tanh(v[i][r]+b1[j]) * w2[j]
    float4 b1a = *(const float4*)(b1s + 8 * jg);
    float4 b1b = *(const float4*)(b1s + 8 * jg + 4);
    float4 w2a = *(const float4*)(w2s + 8 * jg);
    float4 w2b = *(const float4*)(w2s + 8 * jg + 4);
    const float b1v[8] = {b1a.x, b1a.y, b1a.z, b1a.w, b1b.x, b1b.y, b1b.z, b1b.w};
    const float w2v[8] = {w2a.x, w2a.y, w2a.z, w2a.w, w2b.x, w2b.y, w2b.z, w2b.w};

    float lanesum = 0.f;
    #pragma unroll
    for (int i = 0; i < 8; i++) {
        int p = pb + i;                      // Lehmer parity
        int d0 = p / 24;  int r0 = p - 24 * d0;
        int d1 = r0 / 6;  int r1 = r0 - 6 * d1;
        int d2 = r1 >> 1; int d3 = r1 & 1;
        float sgn = ((d0 + d1 + d2 + d3) & 1) ? -1.f : 1.f;
        if (wave == 1 && pg == 0) sgn = 0.f; // duplicate tile (perms 56-63)
        float si = 0.f;
        #pragma unroll
        for (int r = 0; r < 8; r++) {
            float vir = (i & 1) ? vp[i >> 1][r].y : vp[i >> 1][r].x;
            si = fmaf(fast_tanh(vir + b1v[r]), w2v[r], si);
        }
        lanesum = fmaf(sgn, si, lanesum);
    }

    double dvj = (double)lanesum;
    #pragma unroll
    for (int off = 32; off > 0; off >>= 1) dvj += __shfl_down(dvj, off, 64);
    if (lane == 0) red_j[s][wave] = dvj;
    __syncthreads();

    // ---- inline combine (R13-validated) ----
    if (t == 0) {
        float ps0 = (float)((red_h[0][0] + red_h[0][1]) + (red_j[0][0] + red_j[0][1]));
        float ps1 = (float)((red_h[1][0] + red_h[1][1]) + (red_j[1][0] + red_j[1][1]));
        float jas = 0.f;
        #pragma unroll
        for (int i = 0; i < 2 * NELEC; i++) jas += jterm[i];
        out[b] = logf(fabsf(ps0 * ps1)) - jas;
    }
    // b2 omitted: sum_p sign_p = 0 kills it exactly.
}

extern "C" void kernel_launch(void* const* d_in, const int* in_sizes, int n_in,
                              void* d_out, int out_size, void* d_ws, size_t ws_size,
                              hipStream_t stream) {
    const float* elec_pos = (const float*)d_in[0];
    const float* ion_pos  = (const float*)d_in[1];
    const float* bf_w     = (const float*)d_in[2];
    const float* bf_b     = (const float*)d_in[3];
    const float* w0       = (const float*)d_in[4];
    const float* b0       = (const float*)d_in[5];
    const float* w1       = (const float*)d_in[6];
    const float* b1       = (const float*)d_in[7];
    const float* w2       = (const float*)d_in[8];
    const float* jk       = (const float*)d_in[10];
    float* out = (float*)d_out;

    const int B = in_sizes[0] / (NELEC * DIM);   // 2048

    hipLaunchKernelGGL(antisym_fused,
                       dim3(B), dim3(256), 0, stream,
                       elec_pos, ion_pos, bf_w, bf_b, w0, b0, w1, b1, w2, jk, out, B);
}